// Round 1
// baseline (7151.366 us; speedup 1.0000x reference)
//
#include <hip/hip_runtime.h>

// Problem constants (from reference)
#define NB 16
#define NS 8
#define NIMG (NB*NS)        // 128 images through the extractor
#define CIN 3
#define HWDIM 128
#define FV 512
#define KOUT 10
#define STRIPS 4            // 4 strips of 8 output rows each (out = 32x32)
#define IN_ROWS 35          // input rows needed per strip: 8*4 + 7 - 4 = 31 -> [y0*4-1, y0*4+33]
#define QW 34               // per-phase column width: padded cols 0..135 -> 34 per phase
#define LDS_ELEMS (CIN*IN_ROWS*4*QW)   // 14280 floats = 57120 B
#define NPASS (FV/16)       // 32 channel-group passes, 16 channels each

// ---------------------------------------------------------------------------
// Kernel 0: transpose conv weights (FV, CIN, 7, 7) -> [oc/16][tap][oc%16]
// so the conv inner loop reads 16 consecutive floats at a wave-uniform address
// (compiler emits s_load -> SGPR broadcast, keeping VALU free for FMA).
// ---------------------------------------------------------------------------
__global__ void wtr_kernel(const float* __restrict__ cw, float* __restrict__ wt) {
    int i = blockIdx.x * 256 + threadIdx.x;
    if (i < FV * 147) {
        int oc = i / 147, tap = i - oc * 147;
        wt[((oc >> 4) * 147 + tap) * 16 + (oc & 15)] = cw[i];
    }
}

// ---------------------------------------------------------------------------
// Kernel 1: fused conv(7x7,s4,SAME) + bias + ReLU + partial avg-pool.
// One WG = (image, strip of 8 output rows). 256 threads = 8x32 output tile.
// Input window staged in LDS phase-split by (col % 4): for tap kx the read
// address is base + ox + (kx>>2) -> lane-stride 1 -> conflict-free.
// Weights: 16 output channels per pass, wave-uniform loads (SGPR).
// Writes per-strip channel sums to ws (deterministic, no atomics).
// ---------------------------------------------------------------------------
__global__ __launch_bounds__(256, 2) void conv_pool_kernel(
    const float* __restrict__ x, const float* __restrict__ wt,
    const float* __restrict__ cb, float* __restrict__ partial)
{
    __shared__ float lds[LDS_ELEMS];
    __shared__ float red[4][16];
    int wg = blockIdx.x;
    int img = wg >> 2;
    int strip = wg & 3;
    int y0 = strip * 8;
    int tid = threadIdx.x;
    const float* ximg = x + (size_t)img * (CIN * HWDIM * HWDIM);
    int gr0 = y0 * 4 - 1;   // SAME padding: pad_lo = 1 (total pad 3: 1 left, 2 right)

    // Stage input window (zero-padded) into phase-split LDS layout
    for (int idx = tid; idx < LDS_ELEMS; idx += 256) {
        int q  = idx % QW;
        int t1 = idx / QW;
        int p  = t1 & 3;
        int t2 = t1 >> 2;
        int rr = t2 % IN_ROWS;
        int ic = t2 / IN_ROWS;
        int ixc = q * 4 + p - 1;          // global col = padded col - 1
        int gr  = gr0 + rr;
        float v = 0.f;
        if (ixc >= 0 && ixc < HWDIM && gr >= 0 && gr < HWDIM)
            v = ximg[(ic * HWDIM + gr) * HWDIM + ixc];
        lds[idx] = v;
    }
    __syncthreads();

    int oy = tid >> 5, ox = tid & 31;     // output position within strip
    int wid = tid >> 6, lane = tid & 63;

    for (int cg = 0; cg < NPASS; ++cg) {
        float acc[16];
#pragma unroll
        for (int g = 0; g < 16; ++g) acc[g] = 0.f;
        const float* wblk = wt + cg * (147 * 16);
#pragma unroll
        for (int ic = 0; ic < CIN; ++ic) {
#pragma unroll
            for (int ky = 0; ky < 7; ++ky) {
                const float* lrow = lds + (ic * IN_ROWS + oy * 4 + ky) * (4 * QW);
                const float* wrow = wblk + (ic * 49 + ky * 7) * 16;
#pragma unroll
                for (int kx = 0; kx < 7; ++kx) {
                    float v = lrow[(kx & 3) * QW + ox + (kx >> 2)];
#pragma unroll
                    for (int g = 0; g < 16; ++g)
                        acc[g] = fmaf(v, wrow[kx * 16 + g], acc[g]);
                }
            }
        }
        // bias + ReLU (per position!) then reduce the 256 positions
#pragma unroll
        for (int g = 0; g < 16; ++g) {
            float r = fmaxf(acc[g] + cb[cg * 16 + g], 0.f);
            r += __shfl_down(r, 32);
            r += __shfl_down(r, 16);
            r += __shfl_down(r, 8);
            r += __shfl_down(r, 4);
            r += __shfl_down(r, 2);
            r += __shfl_down(r, 1);
            if (lane == 0) red[wid][g] = r;
        }
        __syncthreads();
        if (tid < 16) {
            float s = red[0][tid] + red[1][tid] + red[2][tid] + red[3][tid];
            partial[(size_t)wg * FV + cg * 16 + tid] = s;
        }
        __syncthreads();
    }
}

// ---------------------------------------------------------------------------
// Kernel 2: per-sample head. Sum strip partials -> fvs (8,512), scores = q0.fvs,
// masked softmax over valid slices, r0 = sum ak*fvs, out = sigmoid(r0 @ W^T + b).
// ---------------------------------------------------------------------------
__global__ __launch_bounds__(256) void head_kernel(
    const float* __restrict__ partial, const int* __restrict__ nslice,
    const float* __restrict__ q0, const float* __restrict__ pw,
    const float* __restrict__ pb, float* __restrict__ out)
{
    __shared__ float fvs[NS][FV];
    __shared__ float sc[NS];
    __shared__ float r0[FV];
    __shared__ float red2[4];
    int b = blockIdx.x;
    int tid = threadIdx.x;

    for (int i = tid; i < NS * FV; i += 256) {
        int s = i >> 9, d = i & 511;
        const float* pp = partial + (size_t)((b * NS + s) * STRIPS) * FV + d;
        float v = pp[0] + pp[FV] + pp[2 * FV] + pp[3 * FV];
        fvs[s][d] = v * (1.f / 1024.f);   // mean over 32x32 positions
    }
    __syncthreads();

    // scores: 8 groups of 32 lanes, group = slice
    int grp = tid >> 5, l32 = tid & 31;
    float sdot = 0.f;
    for (int d = l32; d < FV; d += 32) sdot += q0[d] * fvs[grp][d];
    sdot += __shfl_down(sdot, 16, 32);
    sdot += __shfl_down(sdot, 8, 32);
    sdot += __shfl_down(sdot, 4, 32);
    sdot += __shfl_down(sdot, 2, 32);
    sdot += __shfl_down(sdot, 1, 32);
    if (l32 == 0) sc[grp] = sdot;
    __syncthreads();

    // masked softmax (uniform across threads, computed redundantly)
    int ns = nslice[b];
    float m = -3.0e38f;
    for (int s = 0; s < NS; ++s) if (s < ns) m = fmaxf(m, sc[s]);
    float ak[NS]; float se = 0.f;
    for (int s = 0; s < NS; ++s) {
        float e = (s < ns) ? expf(sc[s] - m) : 0.f;
        ak[s] = e; se += e;
    }
    float inv = 1.f / se;

    for (int d = tid; d < FV; d += 256) {
        float v = 0.f;
        for (int s = 0; s < NS; ++s) v += ak[s] * fvs[s][d];
        r0[d] = v * inv;
    }
    __syncthreads();

    int wid = tid >> 6, lane = tid & 63;
    for (int k = 0; k < KOUT; ++k) {
        float p = 0.f;
        for (int d = tid; d < FV; d += 256) p += r0[d] * pw[k * FV + d];
        p += __shfl_down(p, 32);
        p += __shfl_down(p, 16);
        p += __shfl_down(p, 8);
        p += __shfl_down(p, 4);
        p += __shfl_down(p, 2);
        p += __shfl_down(p, 1);
        if (lane == 0) red2[wid] = p;
        __syncthreads();
        if (tid == 0) {
            float t = red2[0] + red2[1] + red2[2] + red2[3] + pb[k];
            out[b * KOUT + k] = 1.f / (1.f + expf(-t));
        }
        __syncthreads();
    }
}

extern "C" void kernel_launch(void* const* d_in, const int* in_sizes, int n_in,
                              void* d_out, int out_size, void* d_ws, size_t ws_size,
                              hipStream_t stream) {
    (void)in_sizes; (void)n_in; (void)out_size; (void)ws_size;
    const float* x      = (const float*)d_in[0];
    const int*   nslice = (const int*)d_in[1];
    const float* cw     = (const float*)d_in[2];
    const float* cb     = (const float*)d_in[3];
    const float* q0     = (const float*)d_in[4];
    const float* pw     = (const float*)d_in[5];
    const float* pb     = (const float*)d_in[6];
    float* out = (float*)d_out;

    float* wt      = (float*)d_ws;          // 512*147 = 75264 floats
    float* partial = wt + FV * 147;         // 128*4*512 = 262144 floats

    wtr_kernel<<<(FV * 147 + 255) / 256, 256, 0, stream>>>(cw, wt);
    conv_pool_kernel<<<NIMG * STRIPS, 256, 0, stream>>>(x, wt, cb, partial);
    head_kernel<<<NB, 256, 0, stream>>>(partial, nslice, q0, pw, pb, out);
}

// Round 2
// 368.023 us; speedup vs baseline: 19.4318x; 19.4318x over previous
//
#include <hip/hip_runtime.h>

// Problem constants
#define NB 16
#define NS 8
#define NIMG (NB*NS)        // 128 images
#define CIN 3
#define HWDIM 128
#define FV 512
#define KOUT 10
#define STRIPS 4            // 4 strips of 8 output rows (out = 32x32, stride-4 7x7 SAME)
#define IN_ROWS 35          // input rows per strip
#define QW 33               // entries per phase row (cols 0..32)
#define ROW_STRIDE (4*QW+1) // 133: 4 phases*33 + 1 pad float -> per-oy bank shift 20 (coprime walk, <=2-way)
#define NROWS (CIN*IN_ROWS) // 105
#define SM_IN_ELEMS (NROWS*4*QW)       // 13860 real elements staged
#define SM_W_OFF 13968                 // 16B-aligned float offset for weight buffer (>= 105*133=13965)
#define KC 7                           // taps per chunk (one (ic,ky) row)
#define NCH_PASS 128                   // channels per pass
#define NPASS 4
#define NSEG (NPASS*21)                // 84 segments; wt2 offset of segment s = s*896 floats

// ---------------------------------------------------------------------------
// Kernel 0: transpose conv weights (FV, CIN*7*7=147) -> [pass(4)][tap(147)][128]
// so each 7-tap chunk is one contiguous, coalesced 3.5KB block.
// ---------------------------------------------------------------------------
__global__ void wtr_kernel(const float* __restrict__ cw, float* __restrict__ wt2) {
    int i = blockIdx.x * 256 + threadIdx.x;
    if (i < FV * 147) {
        int oc = i / 147, tap = i - oc * 147;
        wt2[((oc >> 7) * 147 + tap) * 128 + (oc & 127)] = cw[i];
    }
}

// ---------------------------------------------------------------------------
// Kernel 1: implicit-GEMM conv(7x7,s4,SAME) + bias + ReLU + partial avg-pool.
// WG = (image, 8-row strip). 256 threads; thread tile = 4 positions x 32 ch.
// Wave w owns channel group w*32 -> weight LDS reads are wave-uniform
// (broadcast, conflict-free). Input from phase-split LDS window: 4 ds_read_b32
// per k-step, 2-way bank aliasing max (free). Weights pipelined global->LDS
// in 7-tap chunks; chunk s+1 loads issue before chunk s computes.
// ---------------------------------------------------------------------------
__global__ __launch_bounds__(256, 2) void conv_pool_kernel(
    const float* __restrict__ x, const float* __restrict__ wt2,
    const float* __restrict__ cb, float* __restrict__ partial)
{
    __shared__ float sm[SM_W_OFF + KC * NCH_PASS];   // 14864 floats = 59456 B
    float* sm_in = sm;
    float* sm_w  = sm + SM_W_OFF;

    int wg = blockIdx.x;
    int img = wg >> 2;
    int strip = wg & 3;
    int tid = threadIdx.x;
    const float* ximg = x + (size_t)img * (CIN * HWDIM * HWDIM);
    int gr0 = strip * 32 - 1;           // SAME pad: 1 top/left, 2 bottom/right

    // ---- stage input window (zero-padded, phase-split by col%4) ----
    for (int i = tid; i < SM_IN_ELEMS; i += 256) {
        int e  = i % QW;
        int t1 = i / QW;
        int p  = t1 & 3;
        int r  = t1 >> 2;               // 0..104 = ic*35 + rr
        int rr = r % IN_ROWS;
        int ic = r / IN_ROWS;
        int col = 4 * e + p - 1;
        int gr  = gr0 + rr;
        float v = 0.f;
        if ((unsigned)col < (unsigned)HWDIM && (unsigned)gr < (unsigned)HWDIM)
            v = ximg[(ic * HWDIM + gr) * HWDIM + col];
        sm_in[r * ROW_STRIDE + p * QW + e] = v;
    }

    int tm = tid & 63, wv = tid >> 6;   // lane, wave(=channel group)
    int oy = tm >> 3, q = tm & 7;       // positions: row oy, cols q+8j (j=0..3)

    float acc[4][32];
#pragma unroll
    for (int j = 0; j < 4; ++j)
#pragma unroll
        for (int ch = 0; ch < 32; ++ch) acc[j][ch] = 0.f;

    // prologue: load weight chunk 0
    float4 wreg;
    if (tid < 224) wreg = *(const float4*)(wt2 + (size_t)tid * 4);

    for (int s = 0; s < NSEG; ++s) {
        __syncthreads();                             // weight buf free
        if (tid < 224) *(float4*)(sm_w + tid * 4) = wreg;
        __syncthreads();
        if (s + 1 < NSEG && tid < 224)               // prefetch next chunk (hides under FMAs)
            wreg = *(const float4*)(wt2 + (size_t)(s + 1) * 896 + tid * 4);

        int c  = s % 21;                             // chunk within pass
        int ic = c / 7, ky = c - 7 * ic;             // chunk = fixed (ic,ky); kx sweeps 0..6
        const float* lrow = sm_in + (ic * IN_ROWS + oy * 4 + ky) * ROW_STRIDE + q;
#pragma unroll
        for (int kx = 0; kx < 7; ++kx) {
            const int p = kx & 3, h = kx >> 2;
            const float* lr = lrow + p * QW + h;
            float v0 = lr[0], v1 = lr[8], v2 = lr[16], v3 = lr[24];
            const float4* wp = (const float4*)(sm_w + kx * NCH_PASS + wv * 32);
#pragma unroll
            for (int jj = 0; jj < 8; ++jj) {
                float4 w = wp[jj];
                float wc[4] = {w.x, w.y, w.z, w.w};
#pragma unroll
                for (int m = 0; m < 4; ++m) {
                    acc[0][4*jj+m] = fmaf(v0, wc[m], acc[0][4*jj+m]);
                    acc[1][4*jj+m] = fmaf(v1, wc[m], acc[1][4*jj+m]);
                    acc[2][4*jj+m] = fmaf(v2, wc[m], acc[2][4*jj+m]);
                    acc[3][4*jj+m] = fmaf(v3, wc[m], acc[3][4*jj+m]);
                }
            }
        }

        if (c == 20) {                               // end of pass: bias+ReLU+pool+reduce
            int pass = s / 21;
            int chbase = pass * NCH_PASS + wv * 32;
#pragma unroll
            for (int ch = 0; ch < 32; ++ch) {
                float b = cb[chbase + ch];
                float r = fmaxf(acc[0][ch] + b, 0.f) + fmaxf(acc[1][ch] + b, 0.f)
                        + fmaxf(acc[2][ch] + b, 0.f) + fmaxf(acc[3][ch] + b, 0.f);
                r += __shfl_down(r, 32);
                r += __shfl_down(r, 16);
                r += __shfl_down(r, 8);
                r += __shfl_down(r, 4);
                r += __shfl_down(r, 2);
                r += __shfl_down(r, 1);
                if (tm == 0) partial[(size_t)wg * FV + chbase + ch] = r;
                acc[0][ch] = 0.f; acc[1][ch] = 0.f; acc[2][ch] = 0.f; acc[3][ch] = 0.f;
            }
        }
    }
}

// ---------------------------------------------------------------------------
// Kernel 2: per-sample head (unchanged from round 1 — exact match).
// ---------------------------------------------------------------------------
__global__ __launch_bounds__(256) void head_kernel(
    const float* __restrict__ partial, const int* __restrict__ nslice,
    const float* __restrict__ q0, const float* __restrict__ pw,
    const float* __restrict__ pb, float* __restrict__ out)
{
    __shared__ float fvs[NS][FV];
    __shared__ float sc[NS];
    __shared__ float r0[FV];
    __shared__ float red2[4];
    int b = blockIdx.x;
    int tid = threadIdx.x;

    for (int i = tid; i < NS * FV; i += 256) {
        int s = i >> 9, d = i & 511;
        const float* pp = partial + (size_t)((b * NS + s) * STRIPS) * FV + d;
        float v = pp[0] + pp[FV] + pp[2 * FV] + pp[3 * FV];
        fvs[s][d] = v * (1.f / 1024.f);
    }
    __syncthreads();

    int grp = tid >> 5, l32 = tid & 31;
    float sdot = 0.f;
    for (int d = l32; d < FV; d += 32) sdot += q0[d] * fvs[grp][d];
    sdot += __shfl_down(sdot, 16, 32);
    sdot += __shfl_down(sdot, 8, 32);
    sdot += __shfl_down(sdot, 4, 32);
    sdot += __shfl_down(sdot, 2, 32);
    sdot += __shfl_down(sdot, 1, 32);
    if (l32 == 0) sc[grp] = sdot;
    __syncthreads();

    int ns = nslice[b];
    float m = -3.0e38f;
    for (int s = 0; s < NS; ++s) if (s < ns) m = fmaxf(m, sc[s]);
    float ak[NS]; float se = 0.f;
    for (int s = 0; s < NS; ++s) {
        float e = (s < ns) ? expf(sc[s] - m) : 0.f;
        ak[s] = e; se += e;
    }
    float inv = 1.f / se;

    for (int d = tid; d < FV; d += 256) {
        float v = 0.f;
        for (int s = 0; s < NS; ++s) v += ak[s] * fvs[s][d];
        r0[d] = v * inv;
    }
    __syncthreads();

    int wid = tid >> 6, lane = tid & 63;
    for (int k = 0; k < KOUT; ++k) {
        float p = 0.f;
        for (int d = tid; d < FV; d += 256) p += r0[d] * pw[k * FV + d];
        p += __shfl_down(p, 32);
        p += __shfl_down(p, 16);
        p += __shfl_down(p, 8);
        p += __shfl_down(p, 4);
        p += __shfl_down(p, 2);
        p += __shfl_down(p, 1);
        if (lane == 0) red2[wid] = p;
        __syncthreads();
        if (tid == 0) {
            float t = red2[0] + red2[1] + red2[2] + red2[3] + pb[k];
            out[b * KOUT + k] = 1.f / (1.f + expf(-t));
        }
        __syncthreads();
    }
}

extern "C" void kernel_launch(void* const* d_in, const int* in_sizes, int n_in,
                              void* d_out, int out_size, void* d_ws, size_t ws_size,
                              hipStream_t stream) {
    (void)in_sizes; (void)n_in; (void)out_size; (void)ws_size;
    const float* x      = (const float*)d_in[0];
    const int*   nslice = (const int*)d_in[1];
    const float* cw     = (const float*)d_in[2];
    const float* cb     = (const float*)d_in[3];
    const float* q0     = (const float*)d_in[4];
    const float* pw     = (const float*)d_in[5];
    const float* pb     = (const float*)d_in[6];
    float* out = (float*)d_out;

    float* wt2     = (float*)d_ws;          // 512*147 = 75264 floats, [pass][tap][128]
    float* partial = wt2 + FV * 147;        // 512*512 floats

    wtr_kernel<<<(FV * 147 + 255) / 256, 256, 0, stream>>>(cw, wt2);
    conv_pool_kernel<<<NIMG * STRIPS, 256, 0, stream>>>(x, wt2, cb, partial);
    head_kernel<<<NB, 256, 0, stream>>>(partial, nslice, q0, pw, pb, out);
}

// Round 3
// 313.702 us; speedup vs baseline: 22.7967x; 1.1732x over previous
//
#include <hip/hip_runtime.h>

// Problem constants
#define NB 16
#define NS 8
#define NIMG (NB*NS)        // 128 images
#define CIN 3
#define HWDIM 128
#define FV 512
#define KOUT 10
#define STRIPS 4            // 4 strips of 8 output rows (out = 32x32, stride-4 7x7 SAME)
#define IN_ROWS 35          // input rows per strip
#define QW 33               // entries per phase row (cols 0..32)
#define ROW_STRIDE (4*QW+1) // 133: per-oy bank shift 20 -> coprime walk, max 2-way (free)
#define NROWS (CIN*IN_ROWS) // 105
#define SM_IN_ELEMS (NROWS*4*QW)   // 13860 real elements staged

// ---------------------------------------------------------------------------
// Kernel 0: transpose conv weights (FV, CIN*7*7=147) -> [pass(4)][tap(147)][128]
// so each k-step's 32-channel weight block is 128B contiguous (s_load_dwordx16 x2).
// ---------------------------------------------------------------------------
__global__ void wtr_kernel(const float* __restrict__ cw, float* __restrict__ wt2) {
    int i = blockIdx.x * 256 + threadIdx.x;
    if (i < FV * 147) {
        int oc = i / 147, tap = i - oc * 147;
        wt2[((oc >> 7) * 147 + tap) * 128 + (oc & 127)] = cw[i];
    }
}

// ---------------------------------------------------------------------------
// Kernel 1: implicit-GEMM conv(7x7,s4,SAME) + bias + ReLU + partial avg-pool.
// WG = (image, 8-row strip). 256 threads; lane tile = 4 positions x 32 channels.
// Weights: wave-uniform indices into wt2 -> scalar loads (SGPR broadcast,
// scalar pipe) -> DS pipe only carries 4 input ds_read_b32 per wave per k-step.
// Input window phase-split by col%4 in LDS, row stride 133 (conflict-free).
// ---------------------------------------------------------------------------
__global__ __launch_bounds__(256, 2) void conv_pool_kernel(
    const float* __restrict__ x, const float* __restrict__ wt2,
    const float* __restrict__ cb, float* __restrict__ partial)
{
    __shared__ float sm_in[NROWS * ROW_STRIDE];     // 13965 floats = 55860 B

    int wg = blockIdx.x;
    int img = wg >> 2;
    int strip = wg & 3;
    int tid = threadIdx.x;
    const float* ximg = x + (size_t)img * (CIN * HWDIM * HWDIM);
    int gr0 = strip * 32 - 1;           // SAME pad: 1 top/left, 2 bottom/right

    // ---- stage input window (zero-padded, phase-split by col%4) ----
    for (int i = tid; i < SM_IN_ELEMS; i += 256) {
        int e  = i % QW;
        int t1 = i / QW;
        int p  = t1 & 3;
        int r  = t1 >> 2;               // 0..104 = ic*35 + rr
        int rr = r % IN_ROWS;
        int ic = r / IN_ROWS;
        int col = 4 * e + p - 1;
        int gr  = gr0 + rr;
        float v = 0.f;
        if ((unsigned)col < (unsigned)HWDIM && (unsigned)gr < (unsigned)HWDIM)
            v = ximg[(ic * HWDIM + gr) * HWDIM + col];
        sm_in[r * ROW_STRIDE + p * QW + e] = v;
    }
    __syncthreads();

    int tm = tid & 63;
    int wvu = __builtin_amdgcn_readfirstlane(tid >> 6);  // wave id, forced uniform
    int oy = tm >> 3, q = tm & 7;       // positions: row oy, cols q+8j (j=0..3)

    float acc[4][32];
#pragma unroll
    for (int j = 0; j < 4; ++j)
#pragma unroll
        for (int ch = 0; ch < 32; ++ch) acc[j][ch] = 0.f;

    for (int pass = 0; pass < 4; ++pass) {
        const float* wpass = wt2 + (size_t)pass * (147 * 128) + wvu * 32;
        for (int c = 0; c < 21; ++c) {           // chunk = (ic,ky); tap = c*7+kx
            int ic = c / 7, ky = c - 7 * ic;
            const float* lrow = sm_in + (ic * IN_ROWS + oy * 4 + ky) * ROW_STRIDE + q;
            const float* wrow = wpass + (size_t)c * 7 * 128;
#pragma unroll
            for (int kx = 0; kx < 7; ++kx) {
                const float* lr = lrow + (kx & 3) * QW + (kx >> 2);
                float v0 = lr[0], v1 = lr[8], v2 = lr[16], v3 = lr[24];
                const float* wk = wrow + kx * 128;   // uniform -> s_load
#pragma unroll
                for (int j = 0; j < 32; ++j) {
                    float w = wk[j];
                    acc[0][j] = fmaf(v0, w, acc[0][j]);
                    acc[1][j] = fmaf(v1, w, acc[1][j]);
                    acc[2][j] = fmaf(v2, w, acc[2][j]);
                    acc[3][j] = fmaf(v3, w, acc[3][j]);
                }
            }
        }
        // end of pass: bias + ReLU (per position) + pool + wave reduce + store
        int chbase = pass * 128 + wvu * 32;
#pragma unroll
        for (int ch = 0; ch < 32; ++ch) {
            float b = cb[chbase + ch];
            float r = fmaxf(acc[0][ch] + b, 0.f) + fmaxf(acc[1][ch] + b, 0.f)
                    + fmaxf(acc[2][ch] + b, 0.f) + fmaxf(acc[3][ch] + b, 0.f);
            r += __shfl_down(r, 32);
            r += __shfl_down(r, 16);
            r += __shfl_down(r, 8);
            r += __shfl_down(r, 4);
            r += __shfl_down(r, 2);
            r += __shfl_down(r, 1);
            if (tm == 0) partial[(size_t)wg * FV + chbase + ch] = r;
            acc[0][ch] = 0.f; acc[1][ch] = 0.f; acc[2][ch] = 0.f; acc[3][ch] = 0.f;
        }
    }
}

// ---------------------------------------------------------------------------
// Kernel 2: per-sample head (unchanged — exact match since round 1).
// ---------------------------------------------------------------------------
__global__ __launch_bounds__(256) void head_kernel(
    const float* __restrict__ partial, const int* __restrict__ nslice,
    const float* __restrict__ q0, const float* __restrict__ pw,
    const float* __restrict__ pb, float* __restrict__ out)
{
    __shared__ float fvs[NS][FV];
    __shared__ float sc[NS];
    __shared__ float r0[FV];
    __shared__ float red2[4];
    int b = blockIdx.x;
    int tid = threadIdx.x;

    for (int i = tid; i < NS * FV; i += 256) {
        int s = i >> 9, d = i & 511;
        const float* pp = partial + (size_t)((b * NS + s) * STRIPS) * FV + d;
        float v = pp[0] + pp[FV] + pp[2 * FV] + pp[3 * FV];
        fvs[s][d] = v * (1.f / 1024.f);
    }
    __syncthreads();

    int grp = tid >> 5, l32 = tid & 31;
    float sdot = 0.f;
    for (int d = l32; d < FV; d += 32) sdot += q0[d] * fvs[grp][d];
    sdot += __shfl_down(sdot, 16, 32);
    sdot += __shfl_down(sdot, 8, 32);
    sdot += __shfl_down(sdot, 4, 32);
    sdot += __shfl_down(sdot, 2, 32);
    sdot += __shfl_down(sdot, 1, 32);
    if (l32 == 0) sc[grp] = sdot;
    __syncthreads();

    int ns = nslice[b];
    float m = -3.0e38f;
    for (int s = 0; s < NS; ++s) if (s < ns) m = fmaxf(m, sc[s]);
    float ak[NS]; float se = 0.f;
    for (int s = 0; s < NS; ++s) {
        float e = (s < ns) ? expf(sc[s] - m) : 0.f;
        ak[s] = e; se += e;
    }
    float inv = 1.f / se;

    for (int d = tid; d < FV; d += 256) {
        float v = 0.f;
        for (int s = 0; s < NS; ++s) v += ak[s] * fvs[s][d];
        r0[d] = v * inv;
    }
    __syncthreads();

    int wid = tid >> 6, lane = tid & 63;
    for (int k = 0; k < KOUT; ++k) {
        float p = 0.f;
        for (int d = tid; d < FV; d += 256) p += r0[d] * pw[k * FV + d];
        p += __shfl_down(p, 32);
        p += __shfl_down(p, 16);
        p += __shfl_down(p, 8);
        p += __shfl_down(p, 4);
        p += __shfl_down(p, 2);
        p += __shfl_down(p, 1);
        if (lane == 0) red2[wid] = p;
        __syncthreads();
        if (tid == 0) {
            float t = red2[0] + red2[1] + red2[2] + red2[3] + pb[k];
            out[b * KOUT + k] = 1.f / (1.f + expf(-t));
        }
        __syncthreads();
    }
}

extern "C" void kernel_launch(void* const* d_in, const int* in_sizes, int n_in,
                              void* d_out, int out_size, void* d_ws, size_t ws_size,
                              hipStream_t stream) {
    (void)in_sizes; (void)n_in; (void)out_size; (void)ws_size;
    const float* x      = (const float*)d_in[0];
    const int*   nslice = (const int*)d_in[1];
    const float* cw     = (const float*)d_in[2];
    const float* cb     = (const float*)d_in[3];
    const float* q0     = (const float*)d_in[4];
    const float* pw     = (const float*)d_in[5];
    const float* pb     = (const float*)d_in[6];
    float* out = (float*)d_out;

    float* wt2     = (float*)d_ws;          // 512*147 floats, [pass][tap][128]
    float* partial = wt2 + FV * 147;        // 512*512 floats

    wtr_kernel<<<(FV * 147 + 255) / 256, 256, 0, stream>>>(cw, wt2);
    conv_pool_kernel<<<NIMG * STRIPS, 256, 0, stream>>>(x, wt2, cb, partial);
    head_kernel<<<NB, 256, 0, stream>>>(partial, nslice, q0, pw, pb, out);
}

// Round 4
// 136.204 us; speedup vs baseline: 52.5050x; 2.3032x over previous
//
#include <hip/hip_runtime.h>

// Problem constants
#define NB 16
#define NS 8
#define NIMG (NB*NS)        // 128 images
#define CIN 3
#define HWDIM 128
#define FV 512
#define KOUT 10
#define STRIPS 4            // strip = 8 output rows (out 32x32, stride-4 7x7 SAME)
#define WIN_ROWS (CIN*35)   // 105 staged rows (35 input rows per channel)
#define WIN_STRIDE 136      // ushorts per row (272 B, 16B-multiple)
#define NKT 6               // K-tiles of 32: 24 kb-blocks of 8 (21 real = ic*7+ky, 3 zero)
#define WTB_ELEMS (NKT*32*64*8)   // 98304 bf16 = 192 KB packed weight fragments

typedef __attribute__((ext_vector_type(8))) short bf16x8;   // 8 bf16 = 4 VGPR
typedef __attribute__((ext_vector_type(4))) float f32x4;    // MFMA acc

__device__ __forceinline__ unsigned short f2bf(float f) {   // RNE fp32->bf16
    unsigned int u = __float_as_uint(f);
    u = (u + 0x7FFFu + ((u >> 16) & 1u)) >> 16;
    return (unsigned short)u;
}

// ---------------------------------------------------------------------------
// Kernel 0: pack weights into MFMA B-fragment order.
// wtb[kt][ntile(32)][lane(64)][8]: lane l of tile (kt,nt) holds
// B[k = kt*32 + (l>>4)*8 + j][oc = nt*16 + (l&15)]; k=(kb=ic*7+ky, kx=j),
// zero for kb>=21 or kx==7. A wave's fragment load = one contiguous 1KB block.
// ---------------------------------------------------------------------------
__global__ void wprep_kernel(const float* __restrict__ cw,
                             unsigned short* __restrict__ wtb) {
    int i = blockIdx.x * 256 + threadIdx.x;        // < 98304
    int j  = i & 7;
    int l  = (i >> 3) & 63;
    int nt = (i >> 9) & 31;
    int kt = i >> 14;
    int oc = nt * 16 + (l & 15);
    int kb = kt * 4 + (l >> 4);
    unsigned short v = 0;
    if (kb < 21 && j < 7) {
        int ic = kb / 7, ky = kb - 7 * ic;
        v = f2bf(cw[(size_t)oc * 147 + ic * 49 + ky * 7 + j]);
    }
    wtb[i] = v;
}

// ---------------------------------------------------------------------------
// Kernel 1: bf16-MFMA implicit-GEMM conv + bias + ReLU + pool partials.
// WG = (image, 8-row strip), 256 threads (4 waves). Input window staged as
// bf16 rows (col c at slot c+1, zero-padded). A k-run of 8 = 8 contiguous
// pixels -> A-frag is a 16B LDS read at row(ic,ky,oy), col 4*ox-1.
// M-tile = 16 positions (fixed oy, even or odd ox) -> lane addr stride 16B.
// Wave owns 2 N-columns of 64 oc; B-frags for a column (24 x bf16x8 = 96
// VGPR) loaded once from global (L2) and reused over 4 M-supertiles.
// ---------------------------------------------------------------------------
__global__ __launch_bounds__(256, 2) void conv_mfma_kernel(
    const float* __restrict__ x, const unsigned short* __restrict__ wtb,
    const float* __restrict__ cb, float* __restrict__ partial)
{
    __shared__ unsigned short win[WIN_ROWS * WIN_STRIDE];   // 28,560 B

    int wg = blockIdx.x, img = wg >> 2, strip = wg & 3, tid = threadIdx.x;
    const float* ximg = x + (size_t)img * (CIN * HWDIM * HWDIM);
    int gr0 = strip * 32 - 1;            // SAME pad: 1 top/left, 2 bottom/right

    // ---- stage bf16 window: row = ic*35+rr, slot s <-> input col s-1 ----
    for (int i = tid; i < WIN_ROWS * WIN_STRIDE; i += 256) {
        int row = i / WIN_STRIDE, s = i - row * WIN_STRIDE;
        int ic = row / 35, rr = row - ic * 35;
        int c = s - 1, gr = gr0 + rr;
        float v = 0.f;
        if ((unsigned)c < (unsigned)HWDIM && (unsigned)gr < (unsigned)HWDIM)
            v = ximg[(ic * HWDIM + gr) * HWDIM + c];
        win[i] = f2bf(v);
    }
    __syncthreads();

    int l = tid & 63, wv = tid >> 6;
    int m15 = l & 15, kgrp = l >> 4;     // fragment row / k-chunk group

    // window row base per k-tile: kb = kt*4+kgrp -> (ic,ky); kb>=21 clamped
    // to (0,0) (finite data; B is zero there so product is 0).
    int rowbase[NKT];
#pragma unroll
    for (int kt = 0; kt < NKT; ++kt) {
        int kb = kt * 4 + kgrp;
        int ic = (kb < 21) ? kb / 7 : 0;
        int ky = (kb < 21) ? kb - 7 * ic : 0;
        rowbase[kt] = ic * 35 + ky;
    }

    for (int ncol = 0; ncol < 2; ++ncol) {
        int nbase = (wv * 2 + ncol) * 64;          // this wave's 64-oc column

        // load all B-fragments for the column: 24 x 1KB coalesced blocks
        bf16x8 bf[NKT][4];
#pragma unroll
        for (int kt = 0; kt < NKT; ++kt)
#pragma unroll
            for (int nt = 0; nt < 4; ++nt) {
                int ntile = (nbase >> 4) + nt;
                bf[kt][nt] = *(const bf16x8*)(wtb +
                    (((size_t)(kt * 32 + ntile) * 64 + l) << 3));
            }
        float bias[4];
#pragma unroll
        for (int nt = 0; nt < 4; ++nt) bias[nt] = cb[nbase + nt * 16 + m15];
        float pool[4] = {0.f, 0.f, 0.f, 0.f};

        for (int mst = 0; mst < 4; ++mst) {        // 4 M-supertiles (2 rows each)
            f32x4 acc[4][4];
            const f32x4 z = {0.f, 0.f, 0.f, 0.f};
#pragma unroll
            for (int mt = 0; mt < 4; ++mt)
#pragma unroll
                for (int nt = 0; nt < 4; ++nt) acc[mt][nt] = z;

#pragma unroll
            for (int kt = 0; kt < NKT; ++kt) {
                bf16x8 at[4];
#pragma unroll
                for (int mt = 0; mt < 4; ++mt) {   // tile: oy = mst*2+(mt>>1), parity mt&1
                    int row = rowbase[kt] + (mst * 2 + (mt >> 1)) * 4;
                    const unsigned short* p = win + row * WIN_STRIDE + 8 * m15 + 4 * (mt & 1);
                    union { unsigned long long q[2]; bf16x8 v; } u;
                    u.q[0] = *(const unsigned long long*)(p);      // 8B-aligned
                    u.q[1] = *(const unsigned long long*)(p + 4);
                    at[mt] = u.v;
                }
#pragma unroll
                for (int mt = 0; mt < 4; ++mt)
#pragma unroll
                    for (int nt = 0; nt < 4; ++nt)
                        acc[mt][nt] = __builtin_amdgcn_mfma_f32_16x16x32_bf16(
                            at[mt], bf[kt][nt], acc[mt][nt], 0, 0, 0);
            }
            // bias + ReLU per conv output, accumulate pool partial per oc
#pragma unroll
            for (int mt = 0; mt < 4; ++mt)
#pragma unroll
                for (int nt = 0; nt < 4; ++nt)
#pragma unroll
                    for (int r = 0; r < 4; ++r)
                        pool[nt] += fmaxf(acc[mt][nt][r] + bias[nt], 0.f);
        }
        // reduce over the 4 k-chunk lane groups (they hold disjoint positions)
#pragma unroll
        for (int nt = 0; nt < 4; ++nt) {
            float v = pool[nt];
            v += __shfl_xor(v, 16);
            v += __shfl_xor(v, 32);
            if (l < 16) partial[(size_t)wg * FV + nbase + nt * 16 + m15] = v;
        }
    }
}

// ---------------------------------------------------------------------------
// Kernel 2: per-sample head (unchanged — exact match since round 1).
// ---------------------------------------------------------------------------
__global__ __launch_bounds__(256) void head_kernel(
    const float* __restrict__ partial, const int* __restrict__ nslice,
    const float* __restrict__ q0, const float* __restrict__ pw,
    const float* __restrict__ pb, float* __restrict__ out)
{
    __shared__ float fvs[NS][FV];
    __shared__ float sc[NS];
    __shared__ float r0[FV];
    __shared__ float red2[4];
    int b = blockIdx.x;
    int tid = threadIdx.x;

    for (int i = tid; i < NS * FV; i += 256) {
        int s = i >> 9, d = i & 511;
        const float* pp = partial + (size_t)((b * NS + s) * STRIPS) * FV + d;
        float v = pp[0] + pp[FV] + pp[2 * FV] + pp[3 * FV];
        fvs[s][d] = v * (1.f / 1024.f);
    }
    __syncthreads();

    int grp = tid >> 5, l32 = tid & 31;
    float sdot = 0.f;
    for (int d = l32; d < FV; d += 32) sdot += q0[d] * fvs[grp][d];
    sdot += __shfl_down(sdot, 16, 32);
    sdot += __shfl_down(sdot, 8, 32);
    sdot += __shfl_down(sdot, 4, 32);
    sdot += __shfl_down(sdot, 2, 32);
    sdot += __shfl_down(sdot, 1, 32);
    if (l32 == 0) sc[grp] = sdot;
    __syncthreads();

    int ns = nslice[b];
    float m = -3.0e38f;
    for (int s = 0; s < NS; ++s) if (s < ns) m = fmaxf(m, sc[s]);
    float ak[NS]; float se = 0.f;
    for (int s = 0; s < NS; ++s) {
        float e = (s < ns) ? expf(sc[s] - m) : 0.f;
        ak[s] = e; se += e;
    }
    float inv = 1.f / se;

    for (int d = tid; d < FV; d += 256) {
        float v = 0.f;
        for (int s = 0; s < NS; ++s) v += ak[s] * fvs[s][d];
        r0[d] = v * inv;
    }
    __syncthreads();

    int wid = tid >> 6, lane = tid & 63;
    for (int k = 0; k < KOUT; ++k) {
        float p = 0.f;
        for (int d = tid; d < FV; d += 256) p += r0[d] * pw[k * FV + d];
        p += __shfl_down(p, 32);
        p += __shfl_down(p, 16);
        p += __shfl_down(p, 8);
        p += __shfl_down(p, 4);
        p += __shfl_down(p, 2);
        p += __shfl_down(p, 1);
        if (lane == 0) red2[wid] = p;
        __syncthreads();
        if (tid == 0) {
            float t = red2[0] + red2[1] + red2[2] + red2[3] + pb[k];
            out[b * KOUT + k] = 1.f / (1.f + expf(-t));
        }
        __syncthreads();
    }
}

extern "C" void kernel_launch(void* const* d_in, const int* in_sizes, int n_in,
                              void* d_out, int out_size, void* d_ws, size_t ws_size,
                              hipStream_t stream) {
    (void)in_sizes; (void)n_in; (void)out_size; (void)ws_size;
    const float* x      = (const float*)d_in[0];
    const int*   nslice = (const int*)d_in[1];
    const float* cw     = (const float*)d_in[2];
    const float* cb     = (const float*)d_in[3];
    const float* q0     = (const float*)d_in[4];
    const float* pw     = (const float*)d_in[5];
    const float* pb     = (const float*)d_in[6];
    float* out = (float*)d_out;

    float* partial = (float*)d_ws;                              // 512*512 f32 = 1 MB
    unsigned short* wtb = (unsigned short*)(partial + (size_t)NIMG * STRIPS * FV);

    wprep_kernel<<<WTB_ELEMS / 256, 256, 0, stream>>>(cw, wtb);
    conv_mfma_kernel<<<NIMG * STRIPS, 256, 0, stream>>>(x, wtb, cb, partial);
    head_kernel<<<NB, 256, 0, stream>>>(partial, nslice, q0, pw, pb, out);
}